// Round 1
// 1508.094 us; speedup vs baseline: 1.7574x; 1.7574x over previous
//
#include <hip/hip_runtime.h>
#include <float.h>
#include <math.h>

#define HIDDEN 256
#define HALF_H 128
#define SB_AG 32   // agents per block in scores_kernel
#define PB    16   // teams per block in proj_kernel

// overflow-safe fast tanh using hw v_exp_f32
__device__ __forceinline__ float fast_tanh(float x) {
    float ax = fabsf(x);
    float e  = __expf(-2.0f * ax);          // in (0,1], never overflows
    float r  = (1.0f - e) / (1.0f + e);
    return copysignf(r, x);
}

// scores = tanh(A@W1+b1)@W2 + b2. No atomics any more (softmax moved to pool).
// block=256. LDS-staged A tile (32x256 fp32 = 32KB, coalesced float4 loads).
// thread (j=tid&127, g=tid>>7) owns W1 column j for agents g*16..g*16+15.
// LDS reads are wave-broadcast ds_read_b128 (all lanes same address -> free).
__global__ void scores_kernel(const float* __restrict__ A,
                              const float* __restrict__ W1,
                              const float* __restrict__ b1,
                              const float* __restrict__ W2,
                              const float* __restrict__ b2,
                              float* __restrict__ scores,
                              int n_agents) {
    __shared__ float sA[SB_AG][HIDDEN];          // 32 KB
    __shared__ float sred[4][16];

    const int  tid = threadIdx.x;
    const long i0  = (long)blockIdx.x * SB_AG;

    // stage tile: 32 rows x 64 float4 = 2048 float4; 8 per thread, coalesced
#pragma unroll
    for (int p = 0; p < 8; ++p) {
        int idx = p * 256 + tid;
        int r = idx >> 6, c = idx & 63;
        long row = i0 + r;
        if (row >= n_agents) row = n_agents - 1;   // clamp (reads only)
        ((float4*)&sA[r][0])[c] = ((const float4*)(A + row * HIDDEN))[c];
    }
    __syncthreads();

    const int j = tid & 127;     // W1 column
    const int g = tid >> 7;      // agent half-group

    float acc[16];
#pragma unroll
    for (int t = 0; t < 16; ++t) acc[t] = 0.0f;

    for (int k = 0; k < HIDDEN; k += 4) {
        float4 w;
        w.x = W1[(k + 0) * HALF_H + j];
        w.y = W1[(k + 1) * HALF_H + j];
        w.z = W1[(k + 2) * HALF_H + j];
        w.w = W1[(k + 3) * HALF_H + j];
#pragma unroll
        for (int t = 0; t < 16; ++t) {
            float4 a = *((const float4*)&sA[g * 16 + t][k]);   // broadcast
            acc[t] += a.x * w.x + a.y * w.y + a.z * w.z + a.w * w.w;
        }
    }

    const float w2  = W2[j];
    const float b1j = b1[j];
    const int   lane = tid & 63;
    const int   wave = tid >> 6;     // 0..3; waves {2g, 2g+1} cover group g

#pragma unroll
    for (int t = 0; t < 16; ++t) {
        float v = fast_tanh(acc[t] + b1j) * w2;
#pragma unroll
        for (int off = 32; off > 0; off >>= 1)
            v += __shfl_down(v, off, 64);
        if (lane == 0) sred[wave][t] = v;
    }
    __syncthreads();

    if (tid < SB_AG) {
        int a  = tid;
        int g2 = a >> 4, t = a & 15;
        long i = i0 + a;
        if (i < n_agents) {
            scores[i] = sred[2 * g2][t] + sred[2 * g2 + 1][t] + b2[0];
        }
    }
}

// ---------------- CSR build: histogram -> scan -> scatter ----------------

__global__ void hist_kernel(const int* __restrict__ team_idx,
                            int* __restrict__ cnt, int n_agents) {
    int i = blockIdx.x * blockDim.x + threadIdx.x;
    if (i < n_agents) atomicAdd(&cnt[team_idx[i]], 1);
}

// per-block (1024 elements) exclusive scan; block totals to bsums
__global__ void scan1_kernel(const int* __restrict__ cnt,
                             int* __restrict__ offs,
                             int* __restrict__ bsums, int n) {
    __shared__ int sh[256];
    const int tid  = threadIdx.x;
    const int base = blockIdx.x * 1024 + tid * 4;

    int c0 = (base + 0 < n) ? cnt[base + 0] : 0;
    int c1 = (base + 1 < n) ? cnt[base + 1] : 0;
    int c2 = (base + 2 < n) ? cnt[base + 2] : 0;
    int c3 = (base + 3 < n) ? cnt[base + 3] : 0;
    int ts = c0 + c1 + c2 + c3;

    sh[tid] = ts;
    __syncthreads();
#pragma unroll
    for (int off = 1; off < 256; off <<= 1) {
        int v = (tid >= off) ? sh[tid - off] : 0;
        __syncthreads();
        sh[tid] += v;
        __syncthreads();
    }
    int incl = sh[tid];
    int excl = incl - ts;
    if (tid == 255) bsums[blockIdx.x] = incl;

    int e = excl;
    if (base + 0 < n) offs[base + 0] = e; e += c0;
    if (base + 1 < n) offs[base + 1] = e; e += c1;
    if (base + 2 < n) offs[base + 2] = e; e += c2;
    if (base + 3 < n) offs[base + 3] = e;
}

// exclusive scan of block sums, in place (nb ~ 98, trivial)
__global__ void scan2_kernel(int* __restrict__ bsums, int nb) {
    if (threadIdx.x == 0 && blockIdx.x == 0) {
        int carry = 0;
        for (int b = 0; b < nb; ++b) {
            int t = bsums[b]; bsums[b] = carry; carry += t;
        }
    }
}

// add block offsets; also init cursor=offs and offs[n]=total
__global__ void scan3_kernel(int* __restrict__ offs,
                             const int* __restrict__ bsums,
                             int* __restrict__ cursor, int n, int total) {
    int i = blockIdx.x * blockDim.x + threadIdx.x;
    if (i < n) {
        int o = offs[i] + bsums[i >> 10];
        offs[i]   = o;
        cursor[i] = o;
        if (i == 0) offs[n] = total;
    }
}

__global__ void scatter_kernel(const int* __restrict__ team_idx,
                               int* __restrict__ cursor,
                               int* __restrict__ list, int n_agents) {
    int i = blockIdx.x * blockDim.x + threadIdx.x;
    if (i < n_agents) {
        int pos = atomicAdd(&cursor[team_idx[i]], 1);
        list[pos] = i;
    }
}

// ---------------- per-team softmax + weighted sum (gather) ----------------
// one wave per team: softmax over its agents' scores entirely in registers,
// agent rows gathered as coalesced 1KB wave loads, team row written ONCE.
// Empty teams write zeros (replaces the out_team memset).
__global__ void pool_kernel(const float* __restrict__ A,
                            const float* __restrict__ scores,
                            const int* __restrict__ offs,
                            const int* __restrict__ list,
                            float* __restrict__ out_team,
                            float* __restrict__ out_attn,
                            int n_teams) {
    const int wid  = (blockIdx.x * blockDim.x + threadIdx.x) >> 6;  // team
    const int lane = threadIdx.x & 63;
    if (wid >= n_teams) return;

    const int beg = offs[wid];
    const int end = offs[wid + 1];

    float4 acc = make_float4(0.f, 0.f, 0.f, 0.f);

    if (beg < end) {
        // pass 1: max (wave-uniform broadcast loads, L1/L2 served)
        float mx = -FLT_MAX;
        for (int a = beg; a < end; ++a)
            mx = fmaxf(mx, scores[list[a]]);
        // pass 2: denom
        float den = 0.0f;
        for (int a = beg; a < end; ++a)
            den += __expf(scores[list[a]] - mx);
        const float inv = 1.0f / den;
        // pass 3: weighted gather-accumulate
        for (int a = beg; a < end; ++a) {
            int   idx = list[a];
            float w   = __expf(scores[idx] - mx) * inv;
            if (lane == 0) out_attn[idx] = w;
            float4 v = ((const float4*)(A + (long)idx * HIDDEN))[lane];
            acc.x += w * v.x; acc.y += w * v.y;
            acc.z += w * v.z; acc.w += w * v.w;
        }
    }
    ((float4*)(out_team + (long)wid * HIDDEN))[lane] = acc;
}

// out_team = relu(out_team @ Wo + bo), in place. LDS-staged team tile.
// block=256, thread j = output column, 16 teams register-blocked.
__global__ void proj_kernel(const float* __restrict__ Wo,
                            const float* __restrict__ bo,
                            float* __restrict__ out_team, int n_teams) {
    __shared__ float sT[PB][HIDDEN];             // 16 KB

    const int  j  = threadIdx.x;                 // 0..255
    const long t0 = (long)blockIdx.x * PB;

    // stage tile: 16 rows x 64 float4 = 1024 float4; 4 per thread, coalesced
#pragma unroll
    for (int p = 0; p < 4; ++p) {
        int idx = p * 256 + j;
        int r = idx >> 6, c = idx & 63;
        long row = t0 + r;
        if (row >= n_teams) row = n_teams - 1;
        ((float4*)&sT[r][0])[c] = ((const float4*)(out_team + row * HIDDEN))[c];
    }
    __syncthreads();

    float acc[PB];
#pragma unroll
    for (int t = 0; t < PB; ++t) acc[t] = 0.0f;

    for (int k = 0; k < HIDDEN; k += 4) {
        float4 w;
        w.x = Wo[(k + 0) * HIDDEN + j];
        w.y = Wo[(k + 1) * HIDDEN + j];
        w.z = Wo[(k + 2) * HIDDEN + j];
        w.w = Wo[(k + 3) * HIDDEN + j];
#pragma unroll
        for (int t = 0; t < PB; ++t) {
            float4 a = *((const float4*)&sT[t][k]);     // broadcast
            acc[t] += a.x * w.x + a.y * w.y + a.z * w.z + a.w * w.w;
        }
    }

    const float bj = bo[j];
#pragma unroll
    for (int t = 0; t < PB; ++t) {
        long tt = t0 + t;
        if (tt < n_teams) {
            float v = acc[t] + bj;
            out_team[tt * HIDDEN + j] = v > 0.0f ? v : 0.0f;
        }
    }
}

extern "C" void kernel_launch(void* const* d_in, const int* in_sizes, int n_in,
                              void* d_out, int out_size, void* d_ws, size_t ws_size,
                              hipStream_t stream) {
    const float* agent_h  = (const float*)d_in[0];
    const int*   team_idx = (const int*)d_in[1];
    const float* W1 = (const float*)d_in[3];
    const float* b1 = (const float*)d_in[4];
    const float* W2 = (const float*)d_in[5];
    const float* b2 = (const float*)d_in[6];
    const float* Wo = (const float*)d_in[7];
    const float* bo = (const float*)d_in[8];

    const int n_agents = in_sizes[0] / HIDDEN;                 // 400000
    const int n_teams  = (out_size - n_agents) / HIDDEN;       // 100000

    float* out_team = (float*)d_out;                           // [n_teams,256]
    float* out_attn = (float*)d_out + (long)n_teams * HIDDEN;  // [n_agents]

    // workspace layout (~4.4 MB)
    float* scores = (float*)d_ws;                  // n_agents
    int*   cnt    = (int*)(scores + n_agents);     // n_teams
    int*   offs   = cnt + n_teams;                 // n_teams + 1
    int*   cursor = offs + n_teams + 1;            // n_teams
    int*   list   = cursor + n_teams;              // n_agents
    int*   bsums  = list + n_agents;               // ceil(n_teams/1024)

    const int nb1 = (n_teams + 1023) / 1024;

    // scores (heaviest compute) first
    scores_kernel<<<(n_agents + SB_AG - 1) / SB_AG, 256, 0, stream>>>(
        agent_h, W1, b1, W2, b2, scores, n_agents);

    // CSR build
    hipMemsetAsync(cnt, 0, (size_t)n_teams * sizeof(int), stream);
    hist_kernel<<<(n_agents + 255) / 256, 256, 0, stream>>>(team_idx, cnt, n_agents);
    scan1_kernel<<<nb1, 256, 0, stream>>>(cnt, offs, bsums, n_teams);
    scan2_kernel<<<1, 64, 0, stream>>>(bsums, nb1);
    scan3_kernel<<<(n_teams + 255) / 256, 256, 0, stream>>>(
        offs, bsums, cursor, n_teams, n_agents);
    scatter_kernel<<<(n_agents + 255) / 256, 256, 0, stream>>>(
        team_idx, cursor, list, n_agents);

    // per-team softmax + weighted gather (one wave per team)
    pool_kernel<<<(n_teams + 3) / 4, 256, 0, stream>>>(
        agent_h, scores, offs, list, out_team, out_attn, n_teams);

    proj_kernel<<<(n_teams + PB - 1) / PB, 256, 0, stream>>>(
        Wo, bo, out_team, n_teams);
}

// Round 2
// 1012.496 us; speedup vs baseline: 2.6177x; 1.4895x over previous
//
#include <hip/hip_runtime.h>
#include <float.h>
#include <math.h>

#define HIDDEN 256
#define HALF_H 128

typedef __attribute__((ext_vector_type(8))) short bf16x8;
typedef __attribute__((ext_vector_type(4))) float f32x4;

// fp32 -> bf16 round-to-nearest-even (bit trick, no header types)
__device__ __forceinline__ ushort f2bf(float x) {
    unsigned u = __float_as_uint(x);
    u += 0x7FFFu + ((u >> 16) & 1u);
    return (ushort)(u >> 16);
}

// overflow-safe fast tanh using hw v_exp_f32
__device__ __forceinline__ float fast_tanh(float x) {
    float ax = fabsf(x);
    float e  = __expf(-2.0f * ax);          // in (0,1], never overflows
    float r  = (1.0f - e) / (1.0f + e);
    return copysignf(r, x);
}

// ---------------------------------------------------------------------------
// Pack W [K x N] fp32 row-major into MFMA B-fragment order (16x16x32 bf16):
// frag f = (nt*KS + ks)*64 + lane ; elem e -> W[ks*32 + (lane>>4)*8 + e][nt*16 + (lane&15)]
// ---------------------------------------------------------------------------
__global__ void pack_b_kernel(const float* __restrict__ W, ushort* __restrict__ dst,
                              int N, int KS) {
    int total = (N / 16) * KS * 64;
    for (int f = blockIdx.x * blockDim.x + threadIdx.x; f < total;
         f += gridDim.x * blockDim.x) {
        int lane = f & 63;
        int t    = f >> 6;
        int ks   = t % KS;
        int nt   = t / KS;
        int col  = nt * 16 + (lane & 15);
        int k0   = ks * 32 + (lane >> 4) * 8;
        ushort o[8];
#pragma unroll
        for (int e = 0; e < 8; ++e) o[e] = f2bf(W[(long)(k0 + e) * N + col]);
        uint4 pk;
        pk.x = (unsigned)o[0] | ((unsigned)o[1] << 16);
        pk.y = (unsigned)o[2] | ((unsigned)o[3] << 16);
        pk.z = (unsigned)o[4] | ((unsigned)o[5] << 16);
        pk.w = (unsigned)o[6] | ((unsigned)o[7] << 16);
        ((uint4*)dst)[f] = pk;
    }
}

// ---------------------------------------------------------------------------
// scores = tanh(A@W1+b1)@W2 + b2 via MFMA bf16.
// block = 256 thr = 4 waves, 64 agents/block (16 per wave), N=128, K=256.
// A tile staged as bf16 in LDS, row stride 264 shorts (528B: conflict-free b128).
// ---------------------------------------------------------------------------
__global__ void scores_kernel(const float* __restrict__ A,
                              const ushort* __restrict__ w1p,
                              const float* __restrict__ b1,
                              const float* __restrict__ W2,
                              const float* __restrict__ b2,
                              float* __restrict__ scores,
                              int n_agents) {
    __shared__ ushort sA[64][264];               // 33 KB
    const int  tid = threadIdx.x;
    const long i0  = (long)blockIdx.x * 64;

    // stage 64 rows x 256 cols fp32 -> bf16 (coalesced float4 loads)
#pragma unroll
    for (int p = 0; p < 16; ++p) {
        int idx = p * 256 + tid;                 // 0..4095
        int r = idx >> 6, c = idx & 63;          // c indexes float4
        long row = i0 + r;
        if (row >= n_agents) row = n_agents - 1;
        float4 v = ((const float4*)(A + row * HIDDEN))[c];
        uint2 pk;
        pk.x = (unsigned)f2bf(v.x) | ((unsigned)f2bf(v.y) << 16);
        pk.y = (unsigned)f2bf(v.z) | ((unsigned)f2bf(v.w) << 16);
        *(uint2*)&sA[r][c * 4] = pk;
    }
    __syncthreads();

    const int lane = tid & 63;
    const int w    = tid >> 6;                   // wave 0..3
    const int l15  = lane & 15;
    const int kg   = lane >> 4;                  // 0..3
    const int wrow = w * 16 + l15;               // A-frag row (agent within block)

    f32x4 acc[8];
#pragma unroll
    for (int nt = 0; nt < 8; ++nt) acc[nt] = (f32x4)0.0f;

#pragma unroll
    for (int ks = 0; ks < 8; ++ks) {
        bf16x8 a = *(const bf16x8*)&sA[wrow][ks * 32 + kg * 8];
#pragma unroll
        for (int nt = 0; nt < 8; ++nt) {
            bf16x8 b = ((const bf16x8*)w1p)[(nt * 8 + ks) * 64 + lane];
            acc[nt] = __builtin_amdgcn_mfma_f32_16x16x32_bf16(a, b, acc[nt], 0, 0, 0);
        }
    }

    // epilogue: score = sum_j tanh(h_j + b1_j) * W2_j + b2
    // D layout: col j = nt*16 + l15 ; row (agent) = kg*4 + r
    float s[4] = {0.f, 0.f, 0.f, 0.f};
#pragma unroll
    for (int nt = 0; nt < 8; ++nt) {
        int   j   = nt * 16 + l15;
        float b1j = b1[j], w2j = W2[j];
#pragma unroll
        for (int r = 0; r < 4; ++r)
            s[r] += fast_tanh(acc[nt][r] + b1j) * w2j;
    }
#pragma unroll
    for (int r = 0; r < 4; ++r) {
        float v = s[r];
        v += __shfl_xor(v, 1, 64);
        v += __shfl_xor(v, 2, 64);
        v += __shfl_xor(v, 4, 64);
        v += __shfl_xor(v, 8, 64);
        if (l15 == 0) {
            long i = i0 + w * 16 + kg * 4 + r;
            if (i < n_agents) scores[i] = v + b2[0];
        }
    }
}

// ---------------- CSR build: histogram -> scan -> scatter ----------------

__global__ void hist_kernel(const int* __restrict__ team_idx,
                            int* __restrict__ cnt, int n_agents) {
    int i = blockIdx.x * blockDim.x + threadIdx.x;
    if (i < n_agents) atomicAdd(&cnt[team_idx[i]], 1);
}

__global__ void scan1_kernel(const int* __restrict__ cnt,
                             int* __restrict__ offs,
                             int* __restrict__ bsums, int n) {
    __shared__ int sh[256];
    const int tid  = threadIdx.x;
    const int base = blockIdx.x * 1024 + tid * 4;

    int c0 = (base + 0 < n) ? cnt[base + 0] : 0;
    int c1 = (base + 1 < n) ? cnt[base + 1] : 0;
    int c2 = (base + 2 < n) ? cnt[base + 2] : 0;
    int c3 = (base + 3 < n) ? cnt[base + 3] : 0;
    int ts = c0 + c1 + c2 + c3;

    sh[tid] = ts;
    __syncthreads();
#pragma unroll
    for (int off = 1; off < 256; off <<= 1) {
        int v = (tid >= off) ? sh[tid - off] : 0;
        __syncthreads();
        sh[tid] += v;
        __syncthreads();
    }
    int incl = sh[tid];
    int excl = incl - ts;
    if (tid == 255) bsums[blockIdx.x] = incl;

    int e = excl;
    if (base + 0 < n) offs[base + 0] = e; e += c0;
    if (base + 1 < n) offs[base + 1] = e; e += c1;
    if (base + 2 < n) offs[base + 2] = e; e += c2;
    if (base + 3 < n) offs[base + 3] = e;
}

__global__ void scan2_kernel(int* __restrict__ bsums, int nb) {
    if (threadIdx.x == 0 && blockIdx.x == 0) {
        int carry = 0;
        for (int b = 0; b < nb; ++b) {
            int t = bsums[b]; bsums[b] = carry; carry += t;
        }
    }
}

__global__ void scan3_kernel(int* __restrict__ offs,
                             const int* __restrict__ bsums,
                             int* __restrict__ cursor, int n, int total) {
    int i = blockIdx.x * blockDim.x + threadIdx.x;
    if (i < n) {
        int o = offs[i] + bsums[i >> 10];
        offs[i]   = o;
        cursor[i] = o;
        if (i == 0) offs[n] = total;
    }
}

__global__ void scatter_kernel(const int* __restrict__ team_idx,
                               int* __restrict__ cursor,
                               int* __restrict__ list, int n_agents) {
    int i = blockIdx.x * blockDim.x + threadIdx.x;
    if (i < n_agents) {
        int pos = atomicAdd(&cursor[team_idx[i]], 1);
        list[pos] = i;
    }
}

// ---------------- per-team softmax + weighted sum (gather) ----------------
__global__ void pool_kernel(const float* __restrict__ A,
                            const float* __restrict__ scores,
                            const int* __restrict__ offs,
                            const int* __restrict__ list,
                            float* __restrict__ out_team,
                            float* __restrict__ out_attn,
                            int n_teams) {
    const int wid  = (blockIdx.x * blockDim.x + threadIdx.x) >> 6;  // team
    const int lane = threadIdx.x & 63;
    if (wid >= n_teams) return;

    const int beg = offs[wid];
    const int end = offs[wid + 1];

    float4 acc = make_float4(0.f, 0.f, 0.f, 0.f);

    if (beg < end) {
        float mx = -FLT_MAX;
        for (int a = beg; a < end; ++a)
            mx = fmaxf(mx, scores[list[a]]);
        float den = 0.0f;
        for (int a = beg; a < end; ++a)
            den += __expf(scores[list[a]] - mx);
        const float inv = 1.0f / den;
        for (int a = beg; a < end; ++a) {
            int   idx = list[a];
            float w   = __expf(scores[idx] - mx) * inv;
            if (lane == 0) out_attn[idx] = w;
            float4 v = ((const float4*)(A + (long)idx * HIDDEN))[lane];
            acc.x += w * v.x; acc.y += w * v.y;
            acc.z += w * v.z; acc.w += w * v.w;
        }
    }
    ((float4*)(out_team + (long)wid * HIDDEN))[lane] = acc;
}

// ---------------------------------------------------------------------------
// out_team = relu(out_team @ Wo + bo), in place, via MFMA bf16.
// block = 256 thr = 4 waves, 64 teams/block, N=256 (16 tiles), K=256.
// In-place safe: block stages its own 64 rows before writing them.
// ---------------------------------------------------------------------------
__global__ void proj_kernel(const ushort* __restrict__ wop,
                            const float* __restrict__ bo,
                            float* __restrict__ T, int n_teams) {
    __shared__ ushort sT[64][264];               // 33 KB
    const int  tid = threadIdx.x;
    const long t0  = (long)blockIdx.x * 64;

#pragma unroll
    for (int p = 0; p < 16; ++p) {
        int idx = p * 256 + tid;
        int r = idx >> 6, c = idx & 63;
        long row = t0 + r;
        if (row >= n_teams) row = n_teams - 1;
        float4 v = ((const float4*)(T + row * HIDDEN))[c];
        uint2 pk;
        pk.x = (unsigned)f2bf(v.x) | ((unsigned)f2bf(v.y) << 16);
        pk.y = (unsigned)f2bf(v.z) | ((unsigned)f2bf(v.w) << 16);
        *(uint2*)&sT[r][c * 4] = pk;
    }
    __syncthreads();

    const int lane = tid & 63;
    const int w    = tid >> 6;
    const int l15  = lane & 15;
    const int kg   = lane >> 4;
    const int wrow = w * 16 + l15;

    f32x4 acc[16];
#pragma unroll
    for (int nt = 0; nt < 16; ++nt) acc[nt] = (f32x4)0.0f;

#pragma unroll
    for (int ks = 0; ks < 8; ++ks) {
        bf16x8 a = *(const bf16x8*)&sT[wrow][ks * 32 + kg * 8];
#pragma unroll
        for (int nt = 0; nt < 16; ++nt) {
            bf16x8 b = ((const bf16x8*)wop)[(nt * 8 + ks) * 64 + lane];
            acc[nt] = __builtin_amdgcn_mfma_f32_16x16x32_bf16(a, b, acc[nt], 0, 0, 0);
        }
    }

#pragma unroll
    for (int nt = 0; nt < 16; ++nt) {
        int   j   = nt * 16 + l15;
        float boj = bo[j];
#pragma unroll
        for (int r = 0; r < 4; ++r) {
            long tt = t0 + w * 16 + kg * 4 + r;
            if (tt < n_teams) {
                float v = acc[nt][r] + boj;
                T[tt * HIDDEN + j] = v > 0.0f ? v : 0.0f;
            }
        }
    }
}

extern "C" void kernel_launch(void* const* d_in, const int* in_sizes, int n_in,
                              void* d_out, int out_size, void* d_ws, size_t ws_size,
                              hipStream_t stream) {
    const float* agent_h  = (const float*)d_in[0];
    const int*   team_idx = (const int*)d_in[1];
    const float* W1 = (const float*)d_in[3];
    const float* b1 = (const float*)d_in[4];
    const float* W2 = (const float*)d_in[5];
    const float* b2 = (const float*)d_in[6];
    const float* Wo = (const float*)d_in[7];
    const float* bo = (const float*)d_in[8];

    const int n_agents = in_sizes[0] / HIDDEN;                 // 400000
    const int n_teams  = (out_size - n_agents) / HIDDEN;       // 100000

    float* out_team = (float*)d_out;                           // [n_teams,256]
    float* out_attn = (float*)d_out + (long)n_teams * HIDDEN;  // [n_agents]

    // workspace layout: packed weights first (16B aligned), then CSR arrays
    ushort* w1p   = (ushort*)d_ws;                 // 8nt*8ks*64*8 = 32768 (64KB)
    ushort* wop   = w1p + 32768;                   // 16nt*8ks*64*8 = 65536 (128KB)
    float*  scores = (float*)(wop + 65536);        // n_agents
    int*    cnt    = (int*)(scores + n_agents);    // n_teams
    int*    offs   = cnt + n_teams;                // n_teams + 1
    int*    cursor = offs + n_teams + 1;           // n_teams
    int*    list   = cursor + n_teams;             // n_agents
    int*    bsums  = list + n_agents;              // ceil(n_teams/1024)

    const int nb1 = (n_teams + 1023) / 1024;

    // pack weights into MFMA B-frag order (tiny, L2-resident afterwards)
    pack_b_kernel<<<16, 256, 0, stream>>>(W1, w1p, HALF_H, 8);
    pack_b_kernel<<<32, 256, 0, stream>>>(Wo, wop, HIDDEN, 8);

    scores_kernel<<<(n_agents + 63) / 64, 256, 0, stream>>>(
        agent_h, w1p, b1, W2, b2, scores, n_agents);

    // CSR build
    hipMemsetAsync(cnt, 0, (size_t)n_teams * sizeof(int), stream);
    hist_kernel<<<(n_agents + 255) / 256, 256, 0, stream>>>(team_idx, cnt, n_agents);
    scan1_kernel<<<nb1, 256, 0, stream>>>(cnt, offs, bsums, n_teams);
    scan2_kernel<<<1, 64, 0, stream>>>(bsums, nb1);
    scan3_kernel<<<(n_teams + 255) / 256, 256, 0, stream>>>(
        offs, bsums, cursor, n_teams, n_agents);
    scatter_kernel<<<(n_agents + 255) / 256, 256, 0, stream>>>(
        team_idx, cursor, list, n_agents);

    pool_kernel<<<(n_teams + 3) / 4, 256, 0, stream>>>(
        agent_h, scores, offs, list, out_team, out_attn, n_teams);

    proj_kernel<<<(n_teams + 63) / 64, 256, 0, stream>>>(
        wop, bo, out_team, n_teams);
}